// Round 1
// baseline (3366.059 us; speedup 1.0000x reference)
//
#include <hip/hip_runtime.h>

#define USER_NUM 100000
#define ITEM_NUM 150000
#define NTOT     250000           // USER_NUM + ITEM_NUM
#define EMB      64
#define NNZ      5000000
#define NROW_ELEMS (NTOT * EMB)   // 16,000,000 floats = 64 MB

// ---------------- pass-through copies: user_cl/item_cl + prototypes ----------
// out[NROW_ELEMS + i] = ego0[i]; out[2*NROW_ELEMS ...] = protos
__global__ void copy_pass(const float* __restrict__ ue,
                          const float* __restrict__ ie,
                          const float* __restrict__ up,
                          const float* __restrict__ ip,
                          float* __restrict__ out) {
    const int CL4 = NROW_ELEMS / 4;            // 4,000,000 float4
    const int U4  = USER_NUM * EMB / 4;        // 1,600,000
    const int P4  = 2048 * 64 / 4;             // 32,768
    int i = blockIdx.x * blockDim.x + threadIdx.x;
    if (i < CL4) {
        float4 v = (i < U4) ? ((const float4*)ue)[i]
                            : ((const float4*)ie)[i - U4];
        ((float4*)(out + NROW_ELEMS))[i] = v;
    } else {
        int j = i - CL4;
        if (j < P4) {
            ((float4*)(out + 2 * NROW_ELEMS))[j] = ((const float4*)up)[j];
        } else if (j < 2 * P4) {
            ((float4*)(out + 2 * NROW_ELEMS + 2048 * 64))[j - P4] =
                ((const float4*)ip)[j - P4];
        }
    }
}

// ---------------- SpMM: one wave per edge, lane = embedding dim --------------
// next[rows[e]*64 + lane] += vals[e] * x[cols[e]*64 + lane]
__global__ void spmm_first(const float* __restrict__ ue,
                           const float* __restrict__ ie,
                           const float* __restrict__ vals,
                           const int*   __restrict__ rows,
                           const int*   __restrict__ cols,
                           float* __restrict__ next) {
    long long t = (long long)blockIdx.x * blockDim.x + threadIdx.x;
    int e    = (int)(t >> 6);
    int lane = (int)(t & 63);
    if (e >= NNZ) return;
    float v = vals[e];
    int r = rows[e];
    int c = cols[e];
    float x = (c < USER_NUM) ? ue[c * EMB + lane]
                             : ie[(c - USER_NUM) * EMB + lane];
    unsafeAtomicAdd(&next[r * EMB + lane], v * x);
}

__global__ void spmm_mid(const float* __restrict__ cur,
                         const float* __restrict__ vals,
                         const int*   __restrict__ rows,
                         const int*   __restrict__ cols,
                         float* __restrict__ next) {
    long long t = (long long)blockIdx.x * blockDim.x + threadIdx.x;
    int e    = (int)(t >> 6);
    int lane = (int)(t & 63);
    if (e >= NNZ) return;
    float v = vals[e];
    int r = rows[e];
    int c = cols[e];
    unsafeAtomicAdd(&next[r * EMB + lane], v * cur[c * EMB + lane]);
}

// ---------------- accumulation passes (float4, 4M threads each) --------------
// acc lives in out[0 : NROW_ELEMS]
__global__ void add_first(float* __restrict__ out,      // = ego0 + l1
                          const float* __restrict__ ue,
                          const float* __restrict__ ie,
                          const float* __restrict__ l1) {
    const int U4 = USER_NUM * EMB / 4;
    int i = blockIdx.x * blockDim.x + threadIdx.x;
    if (i >= NROW_ELEMS / 4) return;
    float4 e0 = (i < U4) ? ((const float4*)ue)[i]
                         : ((const float4*)ie)[i - U4];
    float4 a = ((const float4*)l1)[i];
    a.x += e0.x; a.y += e0.y; a.z += e0.z; a.w += e0.w;
    ((float4*)out)[i] = a;
}

__global__ void add_mid(float* __restrict__ out,        // out += l2; zero ws0
                        const float* __restrict__ l2,
                        float* __restrict__ zero_me) {
    int i = blockIdx.x * blockDim.x + threadIdx.x;
    if (i >= NROW_ELEMS / 4) return;
    float4 a = ((const float4*)out)[i];
    float4 b = ((const float4*)l2)[i];
    a.x += b.x; a.y += b.y; a.z += b.z; a.w += b.w;
    ((float4*)out)[i] = a;
    ((float4*)zero_me)[i] = make_float4(0.f, 0.f, 0.f, 0.f);
}

__global__ void add_last(float* __restrict__ out,       // out = (out + l3)/4
                         const float* __restrict__ l3) {
    int i = blockIdx.x * blockDim.x + threadIdx.x;
    if (i >= NROW_ELEMS / 4) return;
    float4 a = ((const float4*)out)[i];
    float4 b = ((const float4*)l3)[i];
    a.x = (a.x + b.x) * 0.25f; a.y = (a.y + b.y) * 0.25f;
    a.z = (a.z + b.z) * 0.25f; a.w = (a.w + b.w) * 0.25f;
    ((float4*)out)[i] = a;
}

extern "C" void kernel_launch(void* const* d_in, const int* in_sizes, int n_in,
                              void* d_out, int out_size, void* d_ws, size_t ws_size,
                              hipStream_t stream) {
    const float* ue   = (const float*)d_in[0];
    const float* ie   = (const float*)d_in[1];
    const float* up   = (const float*)d_in[2];
    const float* ip   = (const float*)d_in[3];
    const float* vals = (const float*)d_in[4];
    const int*   rows = (const int*)d_in[5];
    const int*   cols = (const int*)d_in[6];
    float* out = (float*)d_out;

    // ws layout: ws0 [64MB] | ws1 [64MB]   (needs 128 MB of scratch)
    float* ws0 = (float*)d_ws;
    float* ws1 = ws0 + NROW_ELEMS;

    // zero both layer buffers (ws is poisoned 0xAA and never re-poisoned;
    // we must re-zero ourselves every call anyway since we reuse them)
    hipMemsetAsync(d_ws, 0, (size_t)2 * NROW_ELEMS * sizeof(float), stream);

    // pass-throughs: cl copies + prototypes
    {
        int total4 = NROW_ELEMS / 4 + 2 * (2048 * 64 / 4);
        int grid = (total4 + 255) / 256;
        copy_pass<<<grid, 256, 0, stream>>>(ue, ie, up, ip, out);
    }

    const int spmm_grid = (int)(((long long)NNZ * 64 + 255) / 256); // 1,250,000
    const int add_grid  = (NROW_ELEMS / 4 + 255) / 256;             // 15,625

    // layer 1: inputs -> ws0 ; acc(out) = ego0 + ws0
    spmm_first<<<spmm_grid, 256, 0, stream>>>(ue, ie, vals, rows, cols, ws0);
    add_first<<<add_grid, 256, 0, stream>>>(out, ue, ie, ws0);

    // layer 2: ws0 -> ws1 ; acc += ws1 ; re-zero ws0 for layer 3
    spmm_mid<<<spmm_grid, 256, 0, stream>>>(ws0, vals, rows, cols, ws1);
    add_mid<<<add_grid, 256, 0, stream>>>(out, ws1, ws0);

    // layer 3: ws1 -> ws0 ; acc = (acc + ws0) * 0.25
    spmm_mid<<<spmm_grid, 256, 0, stream>>>(ws1, vals, rows, cols, ws0);
    add_last<<<add_grid, 256, 0, stream>>>(out, ws0);
}

// Round 2
// 1098.953 us; speedup vs baseline: 3.0630x; 3.0630x over previous
//
#include <hip/hip_runtime.h>

#define USER_NUM 100000
#define ITEM_NUM 150000
#define NTOT     250000           // USER_NUM + ITEM_NUM
#define EMB      64
#define NNZ      5000000
#define NROW_ELEMS (NTOT * EMB)   // 16,000,000 floats = 64 MB
#define CHUNK    2048
#define NCHUNKS  ((NTOT + CHUNK - 1) / CHUNK)   // 123

// ============================ CSR build pipeline =============================

__global__ void hist_kernel(const int* __restrict__ rows, int* __restrict__ counts) {
    int e = blockIdx.x * blockDim.x + threadIdx.x;
    if (e < NNZ) atomicAdd(&counts[rows[e]], 1);
}

// per-chunk sums (CHUNK=2048 counts per block, 256 threads x 8 elems)
__global__ void scan_partial(const int* __restrict__ counts, int* __restrict__ csum) {
    __shared__ int sm[256];
    int b = blockIdx.x, t = threadIdx.x;
    int base = b * CHUNK + t * 8;
    int s = 0;
#pragma unroll
    for (int k = 0; k < 8; ++k) {
        int idx = base + k;
        if (idx < NTOT) s += counts[idx];
    }
    sm[t] = s; __syncthreads();
    for (int off = 128; off > 0; off >>= 1) {
        if (t < off) sm[t] += sm[t + off];
        __syncthreads();
    }
    if (t == 0) csum[b] = sm[0];
}

// serial exclusive scan over 123 chunk sums (tiny)
__global__ void scan_chunks(const int* __restrict__ csum, int* __restrict__ coff,
                            int* __restrict__ offs) {
    if (blockIdx.x == 0 && threadIdx.x == 0) {
        int run = 0;
        for (int i = 0; i < NCHUNKS; ++i) { coff[i] = run; run += csum[i]; }
        offs[NTOT] = run;   // == NNZ
    }
}

// per-chunk exclusive scan -> global row offsets; also init cursor copy
__global__ void scan_final(const int* __restrict__ counts, const int* __restrict__ coff,
                           int* __restrict__ offs, int* __restrict__ cursor) {
    __shared__ int sm[256];
    int b = blockIdx.x, t = threadIdx.x;
    int base = b * CHUNK + t * 8;
    int c[8]; int T = 0;
#pragma unroll
    for (int k = 0; k < 8; ++k) {
        int idx = base + k;
        c[k] = (idx < NTOT) ? counts[idx] : 0;
        T += c[k];
    }
    sm[t] = T; __syncthreads();
    // Hillis-Steele inclusive scan over 256 thread-sums
    for (int off = 1; off < 256; off <<= 1) {
        int v = (t >= off) ? sm[t - off] : 0;
        __syncthreads();
        sm[t] += v;
        __syncthreads();
    }
    int run = coff[b] + (sm[t] - T);   // chunk base + exclusive offset
#pragma unroll
    for (int k = 0; k < 8; ++k) {
        int idx = base + k;
        if (idx < NTOT) { offs[idx] = run; cursor[idx] = run; run += c[k]; }
    }
}

// scatter edges into row-sorted order, packed (col, val) per edge
__global__ void scatter_kernel(const int* __restrict__ rows, const int* __restrict__ cols,
                               const float* __restrict__ vals, int* __restrict__ cursor,
                               int2* __restrict__ epk) {
    int e = blockIdx.x * blockDim.x + threadIdx.x;
    if (e >= NNZ) return;
    int r = rows[e];
    int p = atomicAdd(&cursor[r], 1);
    epk[p] = make_int2(cols[e], __float_as_int(vals[e]));
}

// ============================ CSR SpMM (no atomics) ==========================
// 16 lanes per row; lane l owns dims [4l, 4l+4) as float4. ~20 edges/row loop.

__device__ __forceinline__ void fmaf4(float4& a, float v, float4 x) {
    a.x += v * x.x; a.y += v * x.y; a.z += v * x.z; a.w += v * x.w;
}

// layer 1: gather from (ue|ie), write l1 -> ws0, acc(out) = ego0 + l1
__global__ void spmm_l1(const float* __restrict__ ue, const float* __restrict__ ie,
                        const int* __restrict__ offs, const int2* __restrict__ epk,
                        float* __restrict__ ws0, float* __restrict__ out) {
    int t = blockIdx.x * blockDim.x + threadIdx.x;
    int r = t >> 4, l = t & 15;
    if (r >= NTOT) return;
    const float4* ue4 = (const float4*)ue;
    const float4* ie4 = (const float4*)ie;
    int beg = offs[r], end = offs[r + 1];
    float4 acc = make_float4(0.f, 0.f, 0.f, 0.f);
    int j = beg;
    for (; j + 1 < end; j += 2) {
        int2 e0 = epk[j], e1 = epk[j + 1];
        int c0 = e0.x, c1 = e1.x;
        float4 x0 = (c0 < USER_NUM) ? ue4[c0 * 16 + l] : ie4[(c0 - USER_NUM) * 16 + l];
        float4 x1 = (c1 < USER_NUM) ? ue4[c1 * 16 + l] : ie4[(c1 - USER_NUM) * 16 + l];
        fmaf4(acc, __int_as_float(e0.y), x0);
        fmaf4(acc, __int_as_float(e1.y), x1);
    }
    if (j < end) {
        int2 e0 = epk[j];
        int c0 = e0.x;
        float4 x0 = (c0 < USER_NUM) ? ue4[c0 * 16 + l] : ie4[(c0 - USER_NUM) * 16 + l];
        fmaf4(acc, __int_as_float(e0.y), x0);
    }
    int idx = r * 16 + l;
    ((float4*)ws0)[idx] = acc;
    float4 e0r = (r < USER_NUM) ? ue4[idx] : ie4[(r - USER_NUM) * 16 + l];
    acc.x += e0r.x; acc.y += e0r.y; acc.z += e0r.z; acc.w += e0r.w;
    ((float4*)out)[idx] = acc;
}

// layer 2: gather from cur, write l2 -> lout, acc(out) += l2
__global__ void spmm_l2(const float* __restrict__ cur, const int* __restrict__ offs,
                        const int2* __restrict__ epk, float* __restrict__ lout,
                        float* __restrict__ out) {
    int t = blockIdx.x * blockDim.x + threadIdx.x;
    int r = t >> 4, l = t & 15;
    if (r >= NTOT) return;
    const float4* x4 = (const float4*)cur;
    int beg = offs[r], end = offs[r + 1];
    float4 acc = make_float4(0.f, 0.f, 0.f, 0.f);
    int j = beg;
    for (; j + 1 < end; j += 2) {
        int2 e0 = epk[j], e1 = epk[j + 1];
        float4 x0 = x4[e0.x * 16 + l];
        float4 x1 = x4[e1.x * 16 + l];
        fmaf4(acc, __int_as_float(e0.y), x0);
        fmaf4(acc, __int_as_float(e1.y), x1);
    }
    if (j < end) {
        int2 e0 = epk[j];
        fmaf4(acc, __int_as_float(e0.y), x4[e0.x * 16 + l]);
    }
    int idx = r * 16 + l;
    ((float4*)lout)[idx] = acc;
    float4 a = ((const float4*)out)[idx];
    a.x += acc.x; a.y += acc.y; a.z += acc.z; a.w += acc.w;
    ((float4*)out)[idx] = a;
}

// layer 3: gather from cur, acc(out) = (acc + l3) * 0.25  (l3 never stored)
__global__ void spmm_l3(const float* __restrict__ cur, const int* __restrict__ offs,
                        const int2* __restrict__ epk, float* __restrict__ out) {
    int t = blockIdx.x * blockDim.x + threadIdx.x;
    int r = t >> 4, l = t & 15;
    if (r >= NTOT) return;
    const float4* x4 = (const float4*)cur;
    int beg = offs[r], end = offs[r + 1];
    float4 acc = make_float4(0.f, 0.f, 0.f, 0.f);
    int j = beg;
    for (; j + 1 < end; j += 2) {
        int2 e0 = epk[j], e1 = epk[j + 1];
        float4 x0 = x4[e0.x * 16 + l];
        float4 x1 = x4[e1.x * 16 + l];
        fmaf4(acc, __int_as_float(e0.y), x0);
        fmaf4(acc, __int_as_float(e1.y), x1);
    }
    if (j < end) {
        int2 e0 = epk[j];
        fmaf4(acc, __int_as_float(e0.y), x4[e0.x * 16 + l]);
    }
    int idx = r * 16 + l;
    float4 a = ((const float4*)out)[idx];
    a.x = (a.x + acc.x) * 0.25f; a.y = (a.y + acc.y) * 0.25f;
    a.z = (a.z + acc.z) * 0.25f; a.w = (a.w + acc.w) * 0.25f;
    ((float4*)out)[idx] = a;
}

// ===================== pass-throughs (written LAST: cl region) ===============
__global__ void copy_pass(const float* __restrict__ ue,
                          const float* __restrict__ ie,
                          const float* __restrict__ up,
                          const float* __restrict__ ip,
                          float* __restrict__ out) {
    const int CL4 = NROW_ELEMS / 4;
    const int U4  = USER_NUM * EMB / 4;
    const int P4  = 2048 * 64 / 4;
    int i = blockIdx.x * blockDim.x + threadIdx.x;
    if (i < CL4) {
        float4 v = (i < U4) ? ((const float4*)ue)[i]
                            : ((const float4*)ie)[i - U4];
        ((float4*)(out + NROW_ELEMS))[i] = v;
    } else {
        int j = i - CL4;
        if (j < P4) {
            ((float4*)(out + 2 * NROW_ELEMS))[j] = ((const float4*)up)[j];
        } else if (j < 2 * P4) {
            ((float4*)(out + 2 * NROW_ELEMS + 2048 * 64))[j - P4] =
                ((const float4*)ip)[j - P4];
        }
    }
}

// =============================================================================
extern "C" void kernel_launch(void* const* d_in, const int* in_sizes, int n_in,
                              void* d_out, int out_size, void* d_ws, size_t ws_size,
                              hipStream_t stream) {
    const float* ue   = (const float*)d_in[0];
    const float* ie   = (const float*)d_in[1];
    const float* up   = (const float*)d_in[2];
    const float* ip   = (const float*)d_in[3];
    const float* vals = (const float*)d_in[4];
    const int*   rows = (const int*)d_in[5];
    const int*   cols = (const int*)d_in[6];
    float* out = (float*)d_out;

    // ws layout (4-byte units):
    //   [0, 16M)                ws0      : layer buffer (64 MB)
    //   [16M, 26M)              epk      : 5M int2 row-sorted edges (40 MB)
    //   [26,000,000 ...]        offs     : NTOT+1
    //   [26,250,112 ...]        cursor   : NTOT
    //   [26,500,224 ...]        counts   : NTOT
    //   [26,750,336 ...]        csum     : NCHUNKS
    //   [26,750,592 ...]        coff     : NCHUNKS
    float* ws0   = (float*)d_ws;
    int2*  epk   = (int2*)((int*)d_ws + 16000000);
    int*   offs  = (int*)d_ws + 26000000;
    int*   cursor= (int*)d_ws + 26250112;
    int*   counts= (int*)d_ws + 26500224;
    int*   csum  = (int*)d_ws + 26750336;
    int*   coff  = (int*)d_ws + 26750592;

    // layer-2 output lives in the user_cl/item_cl region of d_out, rewritten
    // with ego0 by copy_pass at the very end.
    float* outCL = out + NROW_ELEMS;

    const int egrid = (NNZ + 255) / 256;             // 19,532
    const int rgrid = (NTOT * 16 + 255) / 256;       // 15,625

    // ---- build row-sorted edge list (every call; deterministic work) ----
    hipMemsetAsync(counts, 0, NTOT * sizeof(int), stream);
    hist_kernel  <<<egrid, 256, 0, stream>>>(rows, counts);
    scan_partial <<<NCHUNKS, 256, 0, stream>>>(counts, csum);
    scan_chunks  <<<1, 64, 0, stream>>>(csum, coff, offs);
    scan_final   <<<NCHUNKS, 256, 0, stream>>>(counts, coff, offs, cursor);
    scatter_kernel<<<egrid, 256, 0, stream>>>(rows, cols, vals, cursor, epk);

    // ---- 3 CSR SpMM layers with fused accumulation ----
    spmm_l1<<<rgrid, 256, 0, stream>>>(ue, ie, offs, epk, ws0, out);
    spmm_l2<<<rgrid, 256, 0, stream>>>(ws0, offs, epk, outCL, out);
    spmm_l3<<<rgrid, 256, 0, stream>>>(outCL, offs, epk, out);

    // ---- pass-through copies last (restores cl region + protos) ----
    {
        int total4 = NROW_ELEMS / 4 + 2 * (2048 * 64 / 4);
        int grid = (total4 + 255) / 256;
        copy_pass<<<grid, 256, 0, stream>>>(ue, ie, up, ip, out);
    }
}